// Round 1
// baseline (983.807 us; speedup 1.0000x reference)
//
#include <hip/hip_runtime.h>
#include <math.h>

namespace {

constexpr int B = 8, T = 10, C = 32, H = 128, W = 128;
constexpr int HW = H * W;            // 16384
constexpr int CHW = C * HW;          // 524288
constexpr long long NSTATE = (long long)B * CHW;  // 4,194,304

constexpr float DF = 0.90483741803595952f;  // exp(-0.1)
constexpr float DL = 0.36787944117144233f;  // exp(-1.0)
constexpr float DE = 0.36787944117144233f;  // exp(-1.0)
constexpr float VE = 10.0f;

__global__ void k_init(float* __restrict__ f, float* __restrict__ l,
                       float* __restrict__ e, float* __restrict__ y) {
  int i = blockIdx.x * 256 + threadIdx.x;
  f[i] = 0.f;
  l[i] = 0.f;
  y[i] = 0.f;
  e[i] = 10.0f;  // V_E / ALPHA_E
}

// s[b][h][w] = sum_c y[b][c][h][w]
__global__ void k_chansum(const float* __restrict__ y, float* __restrict__ s) {
  int i = blockIdx.x * 256 + threadIdx.x;  // over B*HW
  int b = i / HW, hw = i % HW;
  const float* yp = y + (size_t)b * CHW + hw;
  float acc = 0.f;
#pragma unroll
  for (int c = 0; c < C; ++c) acc += yp[c * HW];
  s[i] = acc;
}

// One recurrence step, fused: conv(y_old, W) + fixed-conv (via s) + state update.
// Block: 256 threads. Tile: 16x16 spatial, all 32 c_out.
// Thread: 4-px w-strip x 8 c_out.
__launch_bounds__(256, 2)
__global__ void k_step(const float* __restrict__ x, const float* __restrict__ wgt,
                       const float* __restrict__ bias, const float* __restrict__ s,
                       const float* __restrict__ y_old, float* __restrict__ y_new,
                       float* __restrict__ f, float* __restrict__ l,
                       float* __restrict__ e, float* __restrict__ out, int t) {
  __shared__ float ys[C][18][19];   // y tile + halo, padded row (bank spread)
  __shared__ float ws2[C][9][C];    // weights re-laid: [c_in][k][c_out]

  const int tid = threadIdx.x;
  const int bid = blockIdx.x;
  const int tw = bid & 7, th = (bid >> 3) & 7, b = bid >> 6;
  const int h0 = th * 16, w0 = tw * 16;

  // stage y tile (with zero halo at image borders)
  for (int i = tid; i < C * 18 * 18; i += 256) {
    int c = i / 324, r = (i % 324) / 18, cl = i % 18;
    int gh = h0 - 1 + r, gw = w0 - 1 + cl;
    float v = 0.f;
    if (gh >= 0 && gh < H && gw >= 0 && gw < W)
      v = y_old[(size_t)b * CHW + (size_t)c * HW + gh * W + gw];
    ys[c][r][cl] = v;
  }
  // stage weights, transposed to [c_in][k][c_out]
  for (int i = tid; i < C * C * 9; i += 256) {
    int co = i / (C * 9);
    int ci = (i / 9) % C;
    int k = i % 9;
    ws2[ci][k][co] = wgt[i];
  }
  __syncthreads();

  const int sidx = tid & 63, g = tid >> 6;   // wave-uniform c_out group
  const int sw = sidx & 3, sh = sidx >> 2;
  const int g8 = g * 8;
  const int gh = h0 + sh, gwc = w0 + sw * 4;

  float acc[8][4];
#pragma unroll
  for (int q = 0; q < 8; ++q)
#pragma unroll
    for (int p = 0; p < 4; ++p) acc[q][p] = 0.f;

  for (int ci = 0; ci < C; ++ci) {
    float yv[3][6];
#pragma unroll
    for (int dh = 0; dh < 3; ++dh)
#pragma unroll
      for (int dx = 0; dx < 6; ++dx)
        yv[dh][dx] = ys[ci][sh + dh][sw * 4 + dx];
#pragma unroll
    for (int k = 0; k < 9; ++k) {
      const int kh = k / 3, kw = k % 3;
      float4 wa = *(const float4*)&ws2[ci][k][g8];
      float4 wb = *(const float4*)&ws2[ci][k][g8 + 4];
      float wv[8] = {wa.x, wa.y, wa.z, wa.w, wb.x, wb.y, wb.z, wb.w};
#pragma unroll
      for (int q = 0; q < 8; ++q)
#pragma unroll
        for (int p = 0; p < 4; ++p)
          acc[q][p] = fmaf(wv[q], yv[kh][p + kw], acc[q][p]);
    }
  }

  // fixed-conv increment from channel-sum s (kernel [[.5,1,.5],[1,0,1],[.5,1,.5]])
  const float* sb = s + (size_t)b * HW;
  auto SV = [&](int hh, int ww) -> float {
    return (hh >= 0 && hh < H && ww >= 0 && ww < W) ? sb[hh * W + ww] : 0.f;
  };
  float linc[4];
#pragma unroll
  for (int p = 0; p < 4; ++p) {
    int gw = gwc + p;
    linc[p] = 0.5f * (SV(gh - 1, gw - 1) + SV(gh - 1, gw + 1) +
                      SV(gh + 1, gw - 1) + SV(gh + 1, gw + 1)) +
              SV(gh - 1, gw) + SV(gh + 1, gw) + SV(gh, gw - 1) + SV(gh, gw + 1);
  }

  // state update + output
#pragma unroll
  for (int q = 0; q < 8; ++q) {
    const int c = g8 + q;
    const size_t idx = (size_t)b * CHW + (size_t)c * HW + (size_t)gh * W + gwc;
    const size_t xidx =
        (((size_t)(b * T + t) * C + c) * (size_t)H + gh) * W + gwc;
    float4 f4 = *(const float4*)(f + idx);
    float4 l4 = *(const float4*)(l + idx);
    float4 e4 = *(const float4*)(e + idx);
    float4 yo4 = *(const float4*)(y_old + idx);
    float4 x4 = *(const float4*)(x + xidx);
    const float bc = bias[c];
    float fr[4] = {f4.x, f4.y, f4.z, f4.w};
    float lr[4] = {l4.x, l4.y, l4.z, l4.w};
    float er[4] = {e4.x, e4.y, e4.z, e4.w};
    float yr[4] = {yo4.x, yo4.y, yo4.z, yo4.w};
    float xr[4] = {x4.x, x4.y, x4.z, x4.w};
    float fo[4], lo_[4], eo[4], yn[4];
#pragma unroll
    for (int p = 0; p < 4; ++p) {
      float fn = DF * fr[p] + acc[q][p] + bc + xr[p];
      float ln = DL * lr[p] + linc[p];
      float u = fn + 0.5f * fn * ln;
      float en = DE * er[p] + VE * yr[p];
      float yv_ = 1.f / (1.f + expf(en - u));
      fo[p] = fn; lo_[p] = ln; eo[p] = en; yn[p] = yv_;
    }
    *(float4*)(f + idx) = make_float4(fo[0], fo[1], fo[2], fo[3]);
    *(float4*)(l + idx) = make_float4(lo_[0], lo_[1], lo_[2], lo_[3]);
    *(float4*)(e + idx) = make_float4(eo[0], eo[1], eo[2], eo[3]);
    *(float4*)(y_new + idx) = make_float4(yn[0], yn[1], yn[2], yn[3]);
    *(float4*)(out + xidx) = make_float4(yn[0], yn[1], yn[2], yn[3]);
  }
}

}  // namespace

extern "C" void kernel_launch(void* const* d_in, const int* in_sizes, int n_in,
                              void* d_out, int out_size, void* d_ws, size_t ws_size,
                              hipStream_t stream) {
  (void)in_sizes; (void)n_in; (void)out_size; (void)ws_size;
  const float* x = (const float*)d_in[0];     // (B,T,C,H,W)
  const float* wgt = (const float*)d_in[1];   // (C,C,3,3)
  const float* bias = (const float*)d_in[2];  // (C,)
  float* out = (float*)d_out;                 // (B,T,C,H,W)

  float* ws = (float*)d_ws;
  float* f = ws;
  float* l = f + NSTATE;
  float* e = l + NSTATE;
  float* y0 = e + NSTATE;
  float* y1 = y0 + NSTATE;
  float* s = y1 + NSTATE;  // B*HW

  k_init<<<(int)(NSTATE / 256), 256, 0, stream>>>(f, l, e, y0);

  float* ycur = y0;
  float* ynxt = y1;
  for (int t = 0; t < T; ++t) {
    k_chansum<<<(B * HW) / 256, 256, 0, stream>>>(ycur, s);
    k_step<<<B * 64, 256, 0, stream>>>(x, wgt, bias, s, ycur, ynxt, f, l, e,
                                       out, t);
    float* tmp = ycur; ycur = ynxt; ynxt = tmp;
  }
}